// Round 13
// baseline (59.264 us; speedup 1.0000x reference)
//
#include <hip/hip_runtime.h>

#define SEQ 2048
#define DIM 6
#define VSTRIDE 2048         // Vt row stride (elements)

typedef _Float16 half4F __attribute__((ext_vector_type(4)));
typedef short bf16x4 __attribute__((ext_vector_type(4)));
typedef float f32x4 __attribute__((ext_vector_type(4)));

union FragU { uint2 u; half4F h; bf16x4 b; };

__device__ __forceinline__ unsigned pkh(float a, float b) {
    return __builtin_bit_cast(unsigned, __builtin_amdgcn_cvt_pkrtz(a, b));
}
// bf16 round-to-nearest-even via integer rounding (finite, non-NaN inputs).
__device__ __forceinline__ unsigned bf16rn(float x) {
    unsigned u = __builtin_bit_cast(unsigned, x);
    return (u + 0x7FFFu + ((u >> 16) & 1u)) >> 16;
}
__device__ __forceinline__ unsigned pkbf(float a, float b) {
    return bf16rn(a) | (bf16rn(b) << 16);
}

__device__ __forceinline__ f32x4 mfma_bf16_(bf16x4 a, bf16x4 b, f32x4 c) {
#if __has_builtin(__builtin_amdgcn_mfma_f32_16x16x16bf16_1k)
    return __builtin_amdgcn_mfma_f32_16x16x16bf16_1k(a, b, c, 0, 0, 0);
#else
    f32x4 d;
    asm("v_mfma_f32_16x16x16_bf16 %0, %1, %2, %3"
        : "=v"(d) : "v"(a), "v"(b), "v"(c));
    return d;
#endif
}

// ws layout:
//   Kp  [B][SEQ][8] fp16 : {k0..k5 (x log2e), bias (0/-1024), 0}   (1 MB)
//   Vt  [B][8][SEQ] bf16 : rows 0..5 = V^T, row 6 = ones, row 7 pad (1 MB)

__launch_bounds__(256)
__global__ void prep_kv(const float* __restrict__ X,
                        const int* __restrict__ mask,
                        const float* __restrict__ Wk, const float* __restrict__ bk,
                        const float* __restrict__ Wv, const float* __restrict__ bv,
                        __fp16* __restrict__ Kp, unsigned short* __restrict__ Vt) {
    const int idx = blockIdx.x * 256 + threadIdx.x;  // (b, t) flattened
    const int b = idx >> 11;
    const int t = idx & (SEQ - 1);
    const float L2E = 1.44269504088896f;

    const float2* xp = reinterpret_cast<const float2*>(X + (size_t)idx * DIM);
    float2 x01 = xp[0], x23 = xp[1], x45 = xp[2];
    float x[DIM] = {x01.x, x01.y, x23.x, x23.y, x45.x, x45.y};
    float kk[DIM], vv[DIM];
#pragma unroll
    for (int r = 0; r < DIM; ++r) {
        float k = bk[r], v = bv[r];
#pragma unroll
        for (int c = 0; c < DIM; ++c) {
            k = fmaf(Wk[r * DIM + c], x[c], k);
            v = fmaf(Wv[r * DIM + c], x[c], v);
        }
        kk[r] = k * L2E;
        vv[r] = v;
    }
    const float bias = (mask[idx] == 0) ? -1024.0f : 0.0f;
    uint4 kw;
    kw.x = pkh(kk[0], kk[1]);
    kw.y = pkh(kk[2], kk[3]);
    kw.z = pkh(kk[4], kk[5]);
    kw.w = pkh(bias, 0.0f);
    *reinterpret_cast<uint4*>(&Kp[(size_t)idx * 8]) = kw;

    unsigned short* vb = Vt + (size_t)b * 8 * VSTRIDE + t;
#pragma unroll
    for (int r = 0; r < DIM; ++r) vb[r * VSTRIDE] = (unsigned short)bf16rn(vv[r]);
    vb[6 * VSTRIDE] = 0x3F80u;  // bf16 1.0
}

// One wave per 16-row s-tile; K/V tiles read straight from L2 (no LDS, no barrier).
__launch_bounds__(256, 4)
__global__ void attn_mfma(const float* __restrict__ X,
                          const int* __restrict__ mask,
                          const float* __restrict__ Wq, const float* __restrict__ bq,
                          const __fp16* __restrict__ Kp,
                          const unsigned short* __restrict__ Vt,
                          float* __restrict__ out) {
    const int tid = threadIdx.x;
    const int lane = tid & 63, wid = tid >> 6;
    const int b = blockIdx.x >> 5;               // 32 blocks (128 tiles) per batch
    const int s0 = ((blockIdx.x & 31) * 4 + wid) * 16;
    const int r15 = lane & 15, g = lane >> 4;
    const int s = s0 + r15;

    const float* Xb = X + (size_t)b * SEQ * DIM;
    const int* mb = mask + (size_t)b * SEQ;

    // Q' projection for row s (4 lane-copies compute the same row)
    float qq[DIM], biasm;
    {
        const float2* xp = reinterpret_cast<const float2*>(Xb + s * DIM);
        float2 x01 = xp[0], x23 = xp[1], x45 = xp[2];
        float x[DIM] = {x01.x, x01.y, x23.x, x23.y, x45.x, x45.y};
        const bool rm = (mb[s] == 0);  // masked row -> p=1 over all t (uniform mean)
#pragma unroll
        for (int r = 0; r < DIM; ++r) {
            float q = bq[r];
#pragma unroll
            for (int c = 0; c < DIM; ++c) q = fmaf(Wq[r * DIM + c], x[c], q);
            qq[r] = rm ? 0.0f : q;
        }
        biasm = rm ? 0.0f : 1.0f;
    }

    FragU qf;
    qf.u.x = (g == 0) ? pkh(qq[0], qq[1]) : (g == 1) ? pkh(qq[4], qq[5]) : 0u;
    qf.u.y = (g == 0) ? pkh(qq[2], qq[3]) : (g == 1) ? pkh(biasm, 0.0f) : 0u;

    const f32x4 zero4 = {0.0f, 0.0f, 0.0f, 0.0f};

    f32x4 acc = zero4;
    {
        const int dcl = (r15 < 6) ? r15 : 6;  // cols 7..15 alias ones row (unused)
        const __fp16* kp = Kp + (size_t)b * SEQ * 8 + r15 * 8 + (g & 1) * 4;
        const unsigned short* vp = Vt + (size_t)b * 8 * VSTRIDE + dcl * VSTRIDE + g * 4;
#pragma unroll 4
        for (int tt = 0; tt < SEQ / 16; ++tt) {
            half4F kf = *reinterpret_cast<const half4F*>(kp);
            bf16x4 vf = *reinterpret_cast<const bf16x4*>(vp);
            f32x4 d = __builtin_amdgcn_mfma_f32_16x16x16f16(kf, qf.h, zero4, 0, 0, 0);
            FragU pa;
            pa.u.x = pkbf(__builtin_amdgcn_exp2f(d[0]), __builtin_amdgcn_exp2f(d[1]));
            pa.u.y = pkbf(__builtin_amdgcn_exp2f(d[2]), __builtin_amdgcn_exp2f(d[3]));
            acc = mfma_bf16_(pa.b, vf, acc);
            kp += 16 * 8;
            vp += 16;
        }
    }

    // ---- Epilogue: divide numerators (cols 0..5) by denominator (col 6) ----
    const int srcl = (lane & 48) | 6;
#pragma unroll
    for (int r = 0; r < 4; ++r) {
        const float dnm = __shfl(acc[r], srcl);
        const float val = acc[r] * __builtin_amdgcn_rcpf(dnm);
        if (r15 < 6) {
            out[((size_t)b * SEQ + s0 + g * 4 + r) * DIM + r15] = val;
        }
    }
}

extern "C" void kernel_launch(void* const* d_in, const int* in_sizes, int n_in,
                              void* d_out, int out_size, void* d_ws, size_t ws_size,
                              hipStream_t stream) {
    const float* X  = (const float*)d_in[0];
    const int* mask = (const int*)d_in[1];
    const float* Wq = (const float*)d_in[2];
    const float* bq = (const float*)d_in[3];
    const float* Wk = (const float*)d_in[4];
    const float* bk = (const float*)d_in[5];
    const float* Wv = (const float*)d_in[6];
    const float* bv = (const float*)d_in[7];
    float* out = (float*)d_out;

    const int B = in_sizes[0] / (SEQ * DIM);

    __fp16* Kp = (__fp16*)d_ws;                                   // B*SEQ*8 fp16
    unsigned short* Vt = (unsigned short*)(Kp + (size_t)B * SEQ * 8);  // B*8*SEQ bf16

    prep_kv<<<dim3(B * SEQ / 256), 256, 0, stream>>>(X, mask, Wk, bk, Wv, bv, Kp, Vt);
    attn_mfma<<<dim3(B * 32), 256, 0, stream>>>(X, mask, Wq, bq, Kp, Vt, out);
}

// Round 14
// 35.736 us; speedup vs baseline: 1.6584x; 1.6584x over previous
//
#include <hip/hip_runtime.h>

#define SEQ 2048
#define DIM 6
#define TSPLIT 4
#define TCH (SEQ / TSPLIT)   // 512 t-rows per chunk
#define NW 8                 // waves per block
#define BLOCK (NW * 64)      // 512 threads
#define VROW (TCH + 8)       // padded V^T row stride (elements)

typedef _Float16 half4F __attribute__((ext_vector_type(4)));
typedef short bf16x4 __attribute__((ext_vector_type(4)));
typedef float f32x4 __attribute__((ext_vector_type(4)));

union FragU { uint2 u; half4F h; bf16x4 b; };

__device__ __forceinline__ unsigned pkh(float a, float b) {
    return __builtin_bit_cast(unsigned, __builtin_amdgcn_cvt_pkrtz(a, b));
}
// bf16 round-to-nearest-even via integer rounding (finite, non-NaN inputs).
__device__ __forceinline__ unsigned bf16rn(float x) {
    unsigned u = __builtin_bit_cast(unsigned, x);
    return (u + 0x7FFFu + ((u >> 16) & 1u)) >> 16;
}
__device__ __forceinline__ unsigned pkbf(float a, float b) {
    return bf16rn(a) | (bf16rn(b) << 16);
}

__device__ __forceinline__ f32x4 mfma_bf16_(bf16x4 a, bf16x4 b, f32x4 c) {
#if __has_builtin(__builtin_amdgcn_mfma_f32_16x16x16bf16_1k)
    return __builtin_amdgcn_mfma_f32_16x16x16bf16_1k(a, b, c, 0, 0, 0);
#else
    f32x4 d;
    asm("v_mfma_f32_16x16x16_bf16 %0, %1, %2, %3"
        : "=v"(d) : "v"(a), "v"(b), "v"(c));
    return d;
#endif
}

// Block = (b, sc, tc): stages K'/V^T for t-chunk tc (15.3 KB LDS), computes
// 256 s-rows (8 waves x two 16-row tiles) over that chunk, writes f32 partials
// {num0..5, den} to ws. Partials combine by pure addition (absolute exp2, no
// max pass -- bf16 PV is overflow-safe). 1024 blocks -> 4/CU -> 8 waves/SIMD.

__launch_bounds__(BLOCK, 8)
__global__ void attn_partial(const float* __restrict__ X,
                             const int* __restrict__ mask,
                             const float* __restrict__ Wq, const float* __restrict__ bq,
                             const float* __restrict__ Wk, const float* __restrict__ bk,
                             const float* __restrict__ Wv, const float* __restrict__ bv,
                             float* __restrict__ partials) {
    __shared__ __align__(16) __fp16 Ksm[TCH * 8];
    __shared__ __align__(16) unsigned short Vtsm[7 * VROW];

    const int b  = blockIdx.x >> 5;
    const int sc = (blockIdx.x >> 2) & 7;
    const int tc = blockIdx.x & 3;
    const int tid = threadIdx.x;
    const float* Xb = X + (size_t)b * SEQ * DIM;
    const int* mb = mask + (size_t)b * SEQ;
    const float L2E = 1.44269504088896f;

    // ---- Stage K' (fp16) and V^T (bf16) for this t-chunk: one pass ----
    {
        const int tg = tc * TCH + tid;
        const float2* xp = reinterpret_cast<const float2*>(Xb + tg * DIM);
        float2 x01 = xp[0], x23 = xp[1], x45 = xp[2];
        float x[DIM] = {x01.x, x01.y, x23.x, x23.y, x45.x, x45.y};
        float kk[DIM], vv[DIM];
#pragma unroll
        for (int r = 0; r < DIM; ++r) {
            float k = bk[r], v = bv[r];
#pragma unroll
            for (int c = 0; c < DIM; ++c) {
                k = fmaf(Wk[r * DIM + c], x[c], k);
                v = fmaf(Wv[r * DIM + c], x[c], v);
            }
            kk[r] = k * L2E;
            vv[r] = v;
        }
        const float bias = (mb[tg] == 0) ? -1024.0f : 0.0f;
        uint4 kw;
        kw.x = pkh(kk[0], kk[1]);
        kw.y = pkh(kk[2], kk[3]);
        kw.z = pkh(kk[4], kk[5]);
        kw.w = pkh(bias, 0.0f);
        *reinterpret_cast<uint4*>(&Ksm[tid * 8]) = kw;
#pragma unroll
        for (int r = 0; r < DIM; ++r)
            Vtsm[r * VROW + tid] = (unsigned short)bf16rn(vv[r]);
        Vtsm[6 * VROW + tid] = 0x3F80u;  // bf16 1.0
    }
    __syncthreads();

    // ---- Per-wave: two 16-row s-tiles sharing every K/V read ----
    const int lane = tid & 63, wid = tid >> 6;
    const int s0 = (sc * NW + wid) * 32;
    const int r15 = lane & 15, g = lane >> 4;

    FragU qfA, qfB;
#pragma unroll
    for (int k2 = 0; k2 < 2; ++k2) {
        const int s = s0 + k2 * 16 + r15;
        const float2* xp = reinterpret_cast<const float2*>(Xb + s * DIM);
        float2 x01 = xp[0], x23 = xp[1], x45 = xp[2];
        float x[DIM] = {x01.x, x01.y, x23.x, x23.y, x45.x, x45.y};
        const bool rm = (mb[s] == 0);  // masked row -> p=1 over all t (uniform mean)
        float qq[DIM];
#pragma unroll
        for (int r = 0; r < DIM; ++r) {
            float q = bq[r];
#pragma unroll
            for (int c = 0; c < DIM; ++c) q = fmaf(Wq[r * DIM + c], x[c], q);
            qq[r] = rm ? 0.0f : q;
        }
        const float biasm = rm ? 0.0f : 1.0f;
        FragU qf;
        qf.u.x = (g == 0) ? pkh(qq[0], qq[1]) : (g == 1) ? pkh(qq[4], qq[5]) : 0u;
        qf.u.y = (g == 0) ? pkh(qq[2], qq[3]) : (g == 1) ? pkh(biasm, 0.0f) : 0u;
        if (k2 == 0) qfA = qf; else qfB = qf;
    }

    const f32x4 zero4 = {0.0f, 0.0f, 0.0f, 0.0f};
    f32x4 accA = zero4, accB = zero4;
    {
        const int dcl = (r15 < 6) ? r15 : 6;
        int kidx = r15 * 8 + (g & 1) * 4;
        int vidx = dcl * VROW + g * 4;
#pragma unroll 2
        for (int tt = 0; tt < TCH / 16; ++tt) {
            half4F kf = *reinterpret_cast<const half4F*>(&Ksm[kidx]);
            bf16x4 vf = *reinterpret_cast<const bf16x4*>(&Vtsm[vidx]);
            f32x4 dA = __builtin_amdgcn_mfma_f32_16x16x16f16(kf, qfA.h, zero4, 0, 0, 0);
            f32x4 dB = __builtin_amdgcn_mfma_f32_16x16x16f16(kf, qfB.h, zero4, 0, 0, 0);
            FragU paA, paB;
            paA.u.x = pkbf(__builtin_amdgcn_exp2f(dA[0]), __builtin_amdgcn_exp2f(dA[1]));
            paA.u.y = pkbf(__builtin_amdgcn_exp2f(dA[2]), __builtin_amdgcn_exp2f(dA[3]));
            paB.u.x = pkbf(__builtin_amdgcn_exp2f(dB[0]), __builtin_amdgcn_exp2f(dB[1]));
            paB.u.y = pkbf(__builtin_amdgcn_exp2f(dB[2]), __builtin_amdgcn_exp2f(dB[3]));
            accA = mfma_bf16_(paA.b, vf, accA);
            accB = mfma_bf16_(paB.b, vf, accB);
            kidx += 128;
            vidx += 16;
        }
    }

    // ---- Write partials: component r15 (0..5 num, 6 den) of each owned row ----
    if (r15 < 7) {
#pragma unroll
        for (int k2 = 0; k2 < 2; ++k2) {
            const f32x4 acc = k2 ? accB : accA;
#pragma unroll
            for (int r = 0; r < 4; ++r) {
                const int s = s0 + k2 * 16 + g * 4 + r;
                partials[(((size_t)b * TSPLIT + tc) * SEQ + s) * 8 + r15] = acc[r];
            }
        }
    }
}

__launch_bounds__(256)
__global__ void attn_reduce(const float* __restrict__ partials,
                            float* __restrict__ out) {
    const int idx = blockIdx.x * 256 + threadIdx.x;  // (b, s) flattened
    const int b = idx >> 11;
    const int s = idx & (SEQ - 1);
    float acc[7] = {0, 0, 0, 0, 0, 0, 0};
#pragma unroll
    for (int tc = 0; tc < TSPLIT; ++tc) {
        const float4* pp = reinterpret_cast<const float4*>(
            partials + (((size_t)b * TSPLIT + tc) * SEQ + s) * 8);
        float4 a0 = pp[0], a1 = pp[1];
        acc[0] += a0.x; acc[1] += a0.y; acc[2] += a0.z; acc[3] += a0.w;
        acc[4] += a1.x; acc[5] += a1.y; acc[6] += a1.z;
    }
    const float inv = 1.0f / acc[6];
    float2* o2 = reinterpret_cast<float2*>(out + (size_t)idx * DIM);
    o2[0] = make_float2(acc[0] * inv, acc[1] * inv);
    o2[1] = make_float2(acc[2] * inv, acc[3] * inv);
    o2[2] = make_float2(acc[4] * inv, acc[5] * inv);
}

extern "C" void kernel_launch(void* const* d_in, const int* in_sizes, int n_in,
                              void* d_out, int out_size, void* d_ws, size_t ws_size,
                              hipStream_t stream) {
    const float* X  = (const float*)d_in[0];
    const int* mask = (const int*)d_in[1];
    const float* Wq = (const float*)d_in[2];
    const float* bq = (const float*)d_in[3];
    const float* Wk = (const float*)d_in[4];
    const float* bk = (const float*)d_in[5];
    const float* Wv = (const float*)d_in[6];
    const float* bv = (const float*)d_in[7];
    float* out = (float*)d_out;
    float* partials = (float*)d_ws;  // [B][TSPLIT][SEQ][8] f32

    const int B = in_sizes[0] / (SEQ * DIM);

    dim3 grid1(B * 8 * TSPLIT);  // (b, sc, tc)
    attn_partial<<<grid1, BLOCK, 0, stream>>>(X, mask, Wq, bq, Wk, bk, Wv, bv,
                                              partials);
    dim3 grid2(B * SEQ / 256);
    attn_reduce<<<grid2, 256, 0, stream>>>(partials, out);
}

// Round 15
// 25.574 us; speedup vs baseline: 2.3174x; 1.3974x over previous
//
#include <hip/hip_runtime.h>

#define SEQ 2048
#define DIM 6
#define NW 8                 // waves per block
#define BLOCK (NW * 64)
#define VROW 2056            // padded V^T row stride in elements (2048 + 8)

typedef _Float16 half4F __attribute__((ext_vector_type(4)));
typedef short bf16x4 __attribute__((ext_vector_type(4)));
typedef float f32x4 __attribute__((ext_vector_type(4)));

union FragU { uint2 u; half4F h; bf16x4 b; };

__device__ __forceinline__ unsigned pkh(float a, float b) {
    return __builtin_bit_cast(unsigned, __builtin_amdgcn_cvt_pkrtz(a, b));
}
// bf16 round-to-nearest-even via integer rounding (staging only; finite inputs).
__device__ __forceinline__ unsigned bf16rn(float x) {
    unsigned u = __builtin_bit_cast(unsigned, x);
    return (u + 0x7FFFu + ((u >> 16) & 1u)) >> 16;
}
// Packed truncating f32->bf16 pair: ONE v_perm_b32. result = hi16(b)<<16 | hi16(a).
// Truncation bias on P cancels between numerator and denominator.
__device__ __forceinline__ unsigned pkbf_trunc(float a, float b) {
    return __builtin_amdgcn_perm(__builtin_bit_cast(unsigned, b),
                                 __builtin_bit_cast(unsigned, a),
                                 0x07060302u);
}

__device__ __forceinline__ f32x4 mfma_bf16_(bf16x4 a, bf16x4 b, f32x4 c) {
#if __has_builtin(__builtin_amdgcn_mfma_f32_16x16x16bf16_1k)
    return __builtin_amdgcn_mfma_f32_16x16x16bf16_1k(a, b, c, 0, 0, 0);
#else
    f32x4 d;
    asm("v_mfma_f32_16x16x16_bf16 %0, %1, %2, %3"
        : "=v"(d) : "v"(a), "v"(b), "v"(c));
    return d;
#endif
}

// K' [t][8] fp16: {k0..k5 (x log2e), bias (0 / -1024), unused}
// Vt [7][VROW] bf16: rows 0..5 = V^T, row 6 = ones (denominator)
// QK MFMA (f16): A=K'-tile, B=Q' -> D[t_loc][s] = log2e*score + bias
// PV MFMA (bf16): A=exp2(D) packed via v_perm, B=Vt-tile -> C[s][d], col6=denom
// No max pass: p = exp2(arg) bounded by ~2^35; bf16/f32 range is plenty.

__launch_bounds__(BLOCK, 4)
__global__ void attn_mfma(const float* __restrict__ X,
                          const int* __restrict__ mask,
                          const float* __restrict__ Wq, const float* __restrict__ bq,
                          const float* __restrict__ Wk, const float* __restrict__ bk,
                          const float* __restrict__ Wv, const float* __restrict__ bv,
                          float* __restrict__ out) {
    __shared__ __align__(16) __fp16 Ksm[SEQ * 8];
    __shared__ __align__(16) unsigned short Vtsm[7 * VROW];

    const int b = blockIdx.x >> 4;   // 16 blocks per batch
    const int tid = threadIdx.x;
    const float* Xb = X + (size_t)b * SEQ * DIM;
    const int* mb = mask + (size_t)b * SEQ;
    const float L2E = 1.44269504088896f;

    // ---- Stage K' (fp16) and V^T (bf16) for this batch ----
#pragma unroll
    for (int i = 0; i < SEQ / BLOCK; ++i) {
        const int t = tid + i * BLOCK;
        const float2* xp = reinterpret_cast<const float2*>(Xb + t * DIM);
        float2 x01 = xp[0], x23 = xp[1], x45 = xp[2];
        float x[DIM] = {x01.x, x01.y, x23.x, x23.y, x45.x, x45.y};
        float kk[DIM], vv[DIM];
#pragma unroll
        for (int r = 0; r < DIM; ++r) {
            float k = bk[r], v = bv[r];
#pragma unroll
            for (int c = 0; c < DIM; ++c) {
                k = fmaf(Wk[r * DIM + c], x[c], k);
                v = fmaf(Wv[r * DIM + c], x[c], v);
            }
            kk[r] = k * L2E;
            vv[r] = v;
        }
        const float bias = (mb[t] == 0) ? -1024.0f : 0.0f;
        uint4 kw;
        kw.x = pkh(kk[0], kk[1]);
        kw.y = pkh(kk[2], kk[3]);
        kw.z = pkh(kk[4], kk[5]);
        kw.w = pkh(bias, 0.0f);
        *reinterpret_cast<uint4*>(&Ksm[t * 8]) = kw;
#pragma unroll
        for (int r = 0; r < DIM; ++r)
            Vtsm[r * VROW + t] = (unsigned short)bf16rn(vv[r]);
        Vtsm[6 * VROW + t] = 0x3F80u;  // bf16 1.0
    }
    __syncthreads();

    // ---- Per-wave: one 16-row s-tile ----
    const int lane = tid & 63, wid = tid >> 6;
    const int s0 = ((blockIdx.x & 15) * NW + wid) * 16;
    const int r15 = lane & 15, g = lane >> 4;
    const int s = s0 + r15;

    // Q' projection for row s (4 lane-copies compute the same row)
    float qq[DIM], biasm;
    {
        const float2* xp = reinterpret_cast<const float2*>(Xb + s * DIM);
        float2 x01 = xp[0], x23 = xp[1], x45 = xp[2];
        float x[DIM] = {x01.x, x01.y, x23.x, x23.y, x45.x, x45.y};
        const bool rm = (mb[s] == 0);  // masked row -> p=1 over all t (uniform mean)
#pragma unroll
        for (int r = 0; r < DIM; ++r) {
            float q = bq[r];
#pragma unroll
            for (int c = 0; c < DIM; ++c) q = fmaf(Wq[r * DIM + c], x[c], q);
            qq[r] = rm ? 0.0f : q;
        }
        biasm = rm ? 0.0f : 1.0f;
    }

    // B-fragment: lane g holds Q'[s][g*4 .. g*4+3]; k-slots 8..15 are zero.
    FragU qf;
    qf.u.x = (g == 0) ? pkh(qq[0], qq[1]) : (g == 1) ? pkh(qq[4], qq[5]) : 0u;
    qf.u.y = (g == 0) ? pkh(qq[2], qq[3]) : (g == 1) ? pkh(biasm, 0.0f) : 0u;

    const f32x4 zero4 = {0.0f, 0.0f, 0.0f, 0.0f};

    // ---- Single pass: QK -> exp2 -> perm-pack -> PV ----
    f32x4 acc = zero4;
    {
        const int dcl = (r15 < 6) ? r15 : 6;  // cols 7..15 alias ones row (unused)
        int kidx = r15 * 8 + (g & 1) * 4;
        int vidx = dcl * VROW + g * 4;
#pragma unroll 4
        for (int tt = 0; tt < SEQ / 16; ++tt) {
            half4F kf = *reinterpret_cast<const half4F*>(&Ksm[kidx]);
            bf16x4 vf = *reinterpret_cast<const bf16x4*>(&Vtsm[vidx]);
            f32x4 d = __builtin_amdgcn_mfma_f32_16x16x16f16(kf, qf.h, zero4, 0, 0, 0);
            FragU pa;  // P in PV A-layout (same lane holds same (s, t_loc))
            pa.u.x = pkbf_trunc(__builtin_amdgcn_exp2f(d[0]),
                                __builtin_amdgcn_exp2f(d[1]));
            pa.u.y = pkbf_trunc(__builtin_amdgcn_exp2f(d[2]),
                                __builtin_amdgcn_exp2f(d[3]));
            acc = mfma_bf16_(pa.b, vf, acc);
            kidx += 128;
            vidx += 16;
        }
    }

    // ---- Epilogue: divide numerators (cols 0..5) by denominator (col 6) ----
    const int srcl = (lane & 48) | 6;
#pragma unroll
    for (int r = 0; r < 4; ++r) {
        const float dnm = __shfl(acc[r], srcl);
        const float val = acc[r] * __builtin_amdgcn_rcpf(dnm);
        if (r15 < 6) {
            out[((size_t)b * SEQ + s0 + g * 4 + r) * DIM + r15] = val;
        }
    }
}

extern "C" void kernel_launch(void* const* d_in, const int* in_sizes, int n_in,
                              void* d_out, int out_size, void* d_ws, size_t ws_size,
                              hipStream_t stream) {
    const float* X  = (const float*)d_in[0];
    const int* mask = (const int*)d_in[1];
    const float* Wq = (const float*)d_in[2];
    const float* bq = (const float*)d_in[3];
    const float* Wk = (const float*)d_in[4];
    const float* bk = (const float*)d_in[5];
    const float* Wv = (const float*)d_in[6];
    const float* bv = (const float*)d_in[7];
    float* out = (float*)d_out;

    const int B = in_sizes[0] / (SEQ * DIM);

    dim3 grid(B * 16);  // 16 blocks per batch, 8 s-tiles (waves) per block
    attn_mfma<<<grid, BLOCK, 0, stream>>>(X, mask, Wq, bq, Wk, bk, Wv, bv, out);
}

// Round 16
// 25.198 us; speedup vs baseline: 2.3520x; 1.0149x over previous
//
#include <hip/hip_runtime.h>

#define SEQ 2048
#define DIM 6
#define NW 8                  // waves per block
#define BLOCK (NW * 64)       // 512 threads
#define VROW 2056             // padded V^T row stride in elements (2048 + 8)

typedef _Float16 half4F __attribute__((ext_vector_type(4)));
typedef _Float16 half8F __attribute__((ext_vector_type(8)));
typedef short bf16x4 __attribute__((ext_vector_type(4)));
typedef short bf16x8 __attribute__((ext_vector_type(8)));
typedef float f32x4 __attribute__((ext_vector_type(4)));

union FragU { uint2 u; half4F h; bf16x4 b; };
union K8 { half8F v; half4F h[2]; };
union V8 { bf16x8 v; bf16x4 h[2]; };

__device__ __forceinline__ unsigned pkh(float a, float b) {
    return __builtin_bit_cast(unsigned, __builtin_amdgcn_cvt_pkrtz(a, b));
}
// bf16 round-to-nearest-even via integer rounding (staging only; finite inputs).
__device__ __forceinline__ unsigned bf16rn(float x) {
    unsigned u = __builtin_bit_cast(unsigned, x);
    return (u + 0x7FFFu + ((u >> 16) & 1u)) >> 16;
}
// Packed truncating f32->bf16 pair: ONE v_perm_b32 (hi16(b)<<16 | hi16(a)).
__device__ __forceinline__ unsigned pkbf_trunc(float a, float b) {
    return __builtin_amdgcn_perm(__builtin_bit_cast(unsigned, b),
                                 __builtin_bit_cast(unsigned, a),
                                 0x07060302u);
}

__device__ __forceinline__ f32x4 mfma_bf16_(bf16x4 a, bf16x4 b, f32x4 c) {
#if __has_builtin(__builtin_amdgcn_mfma_f32_16x16x16bf16_1k)
    return __builtin_amdgcn_mfma_f32_16x16x16bf16_1k(a, b, c, 0, 0, 0);
#else
    f32x4 d;
    asm("v_mfma_f32_16x16x16_bf16 %0, %1, %2, %3"
        : "=v"(d) : "v"(a), "v"(b), "v"(c));
    return d;
#endif
}

// KsmI [tt2][r][16] fp16, pair-interleaved: {a[0:4], b[0:4], a[4:8], b[4:8]}
//   where a = K'[tt2*32+r], b = K'[tt2*32+16+r]  (K' = {k*log2e x6, bias, 0})
// Vtsm [dcl][VROW] bf16, pair-interleaved within each 32: pos = gv*8 + tile*4 + j
//   rows 0..5 = V^T, row 6 = ones (denominator)
// One ds_read_b128 per K / per V serves TWO t-tiles; each wave owns TWO s-tiles.

__launch_bounds__(BLOCK, 1)
__global__ void attn_mfma(const float* __restrict__ X,
                          const int* __restrict__ mask,
                          const float* __restrict__ Wq, const float* __restrict__ bq,
                          const float* __restrict__ Wk, const float* __restrict__ bk,
                          const float* __restrict__ Wv, const float* __restrict__ bv,
                          float* __restrict__ out) {
    __shared__ __align__(16) __fp16 KsmI[(SEQ / 32) * 16 * 16];  // 32 KB
    __shared__ __align__(16) unsigned short Vtsm[7 * VROW];      // 28.8 KB

    const int b = blockIdx.x >> 3;   // 8 blocks per batch
    const int tid = threadIdx.x;
    const float* Xb = X + (size_t)b * SEQ * DIM;
    const int* mb = mask + (size_t)b * SEQ;
    const float L2E = 1.44269504088896f;

    // ---- Stage K' (interleaved fp16) and V^T (interleaved bf16) ----
#pragma unroll
    for (int i = 0; i < SEQ / BLOCK; ++i) {
        const int t = tid + i * BLOCK;
        const float2* xp = reinterpret_cast<const float2*>(Xb + t * DIM);
        float2 x01 = xp[0], x23 = xp[1], x45 = xp[2];
        float x[DIM] = {x01.x, x01.y, x23.x, x23.y, x45.x, x45.y};
        float kk[DIM], vv[DIM];
#pragma unroll
        for (int r = 0; r < DIM; ++r) {
            float k = bk[r], v = bv[r];
#pragma unroll
            for (int c = 0; c < DIM; ++c) {
                k = fmaf(Wk[r * DIM + c], x[c], k);
                v = fmaf(Wv[r * DIM + c], x[c], v);
            }
            kk[r] = k * L2E;
            vv[r] = v;
        }
        const float bias = (mb[t] == 0) ? -1024.0f : 0.0f;
        // K interleaved write: row t -> [tt2][t&15], a/b half by bit 4 of t.
        {
            const int tt2 = t >> 5, rr = t & 15, hb = (t >> 4) & 1;
            __fp16* kb = &KsmI[((tt2 * 16 + rr) * 16) + hb * 4];
            *reinterpret_cast<uint2*>(kb) = make_uint2(pkh(kk[0], kk[1]),
                                                       pkh(kk[2], kk[3]));
            *reinterpret_cast<uint2*>(kb + 8) = make_uint2(pkh(kk[4], kk[5]),
                                                           pkh(bias, 0.0f));
        }
        // V interleaved write: element t of row r -> gv-major within each 32.
        {
            const int base = t & ~31, rem = t & 31;
            const int tile = rem >> 4, k = rem & 15;
            const int pos = base | ((k >> 2) << 3) | (tile << 2) | (k & 3);
#pragma unroll
            for (int r = 0; r < DIM; ++r)
                Vtsm[r * VROW + pos] = (unsigned short)bf16rn(vv[r]);
            Vtsm[6 * VROW + pos] = 0x3F80u;  // bf16 1.0
        }
    }
    __syncthreads();

    // ---- Per-wave: two 16-row s-tiles (rows s0..s0+31) ----
    const int lane = tid & 63, wid = tid >> 6;
    const int s0 = ((blockIdx.x & 7) * NW + wid) * 32;
    const int r15 = lane & 15, g = lane >> 4;

    FragU qfA, qfB;
#pragma unroll
    for (int k2 = 0; k2 < 2; ++k2) {
        const int s = s0 + k2 * 16 + r15;
        const float2* xp = reinterpret_cast<const float2*>(Xb + s * DIM);
        float2 x01 = xp[0], x23 = xp[1], x45 = xp[2];
        float x[DIM] = {x01.x, x01.y, x23.x, x23.y, x45.x, x45.y};
        const bool rm = (mb[s] == 0);  // masked row -> p=1 over all t (uniform mean)
        float qq[DIM];
#pragma unroll
        for (int r = 0; r < DIM; ++r) {
            float q = bq[r];
#pragma unroll
            for (int c = 0; c < DIM; ++c) q = fmaf(Wq[r * DIM + c], x[c], q);
            qq[r] = rm ? 0.0f : q;
        }
        const float biasm = rm ? 0.0f : 1.0f;
        FragU qf;
        qf.u.x = (g == 0) ? pkh(qq[0], qq[1]) : (g == 1) ? pkh(qq[4], qq[5]) : 0u;
        qf.u.y = (g == 0) ? pkh(qq[2], qq[3]) : (g == 1) ? pkh(biasm, 0.0f) : 0u;
        if (k2 == 0) qfA = qf; else qfB = qf;
    }

    const f32x4 zero4 = {0.0f, 0.0f, 0.0f, 0.0f};
    f32x4 accA = zero4, accB = zero4;
    {
        const int dcl = (r15 < 6) ? r15 : 6;
        int kidx = (r15 * 16) + (g & 1) * 8;   // halves within [tt2] block of 256
        int vidx = dcl * VROW + g * 8;
#pragma unroll 2
        for (int tt2 = 0; tt2 < SEQ / 32; ++tt2) {
            K8 kf2; V8 vf2;
            kf2.v = *reinterpret_cast<const half8F*>(&KsmI[kidx]);
            vf2.v = *reinterpret_cast<const bf16x8*>(&Vtsm[vidx]);
            // QK for (s-tile, t-tile) x 4
            f32x4 dAa = __builtin_amdgcn_mfma_f32_16x16x16f16(kf2.h[0], qfA.h, zero4, 0, 0, 0);
            f32x4 dBa = __builtin_amdgcn_mfma_f32_16x16x16f16(kf2.h[0], qfB.h, zero4, 0, 0, 0);
            f32x4 dAb = __builtin_amdgcn_mfma_f32_16x16x16f16(kf2.h[1], qfA.h, zero4, 0, 0, 0);
            f32x4 dBb = __builtin_amdgcn_mfma_f32_16x16x16f16(kf2.h[1], qfB.h, zero4, 0, 0, 0);
            FragU pAa, pBa, pAb, pBb;
            pAa.u.x = pkbf_trunc(__builtin_amdgcn_exp2f(dAa[0]), __builtin_amdgcn_exp2f(dAa[1]));
            pAa.u.y = pkbf_trunc(__builtin_amdgcn_exp2f(dAa[2]), __builtin_amdgcn_exp2f(dAa[3]));
            pBa.u.x = pkbf_trunc(__builtin_amdgcn_exp2f(dBa[0]), __builtin_amdgcn_exp2f(dBa[1]));
            pBa.u.y = pkbf_trunc(__builtin_amdgcn_exp2f(dBa[2]), __builtin_amdgcn_exp2f(dBa[3]));
            pAb.u.x = pkbf_trunc(__builtin_amdgcn_exp2f(dAb[0]), __builtin_amdgcn_exp2f(dAb[1]));
            pAb.u.y = pkbf_trunc(__builtin_amdgcn_exp2f(dAb[2]), __builtin_amdgcn_exp2f(dAb[3]));
            pBb.u.x = pkbf_trunc(__builtin_amdgcn_exp2f(dBb[0]), __builtin_amdgcn_exp2f(dBb[1]));
            pBb.u.y = pkbf_trunc(__builtin_amdgcn_exp2f(dBb[2]), __builtin_amdgcn_exp2f(dBb[3]));
            accA = mfma_bf16_(pAa.b, vf2.h[0], accA);
            accB = mfma_bf16_(pBa.b, vf2.h[0], accB);
            accA = mfma_bf16_(pAb.b, vf2.h[1], accA);
            accB = mfma_bf16_(pBb.b, vf2.h[1], accB);
            kidx += 256;
            vidx += 32;
        }
    }

    // ---- Epilogue: divide numerators (cols 0..5) by denominator (col 6) ----
    const int srcl = (lane & 48) | 6;
#pragma unroll
    for (int k2 = 0; k2 < 2; ++k2) {
        const f32x4 acc = k2 ? accB : accA;
#pragma unroll
        for (int r = 0; r < 4; ++r) {
            const float dnm = __shfl(acc[r], srcl);
            const float val = acc[r] * __builtin_amdgcn_rcpf(dnm);
            if (r15 < 6) {
                out[((size_t)b * SEQ + s0 + k2 * 16 + g * 4 + r) * DIM + r15] = val;
            }
        }
    }
}

extern "C" void kernel_launch(void* const* d_in, const int* in_sizes, int n_in,
                              void* d_out, int out_size, void* d_ws, size_t ws_size,
                              hipStream_t stream) {
    const float* X  = (const float*)d_in[0];
    const int* mask = (const int*)d_in[1];
    const float* Wq = (const float*)d_in[2];
    const float* bq = (const float*)d_in[3];
    const float* Wk = (const float*)d_in[4];
    const float* bk = (const float*)d_in[5];
    const float* Wv = (const float*)d_in[6];
    const float* bv = (const float*)d_in[7];
    float* out = (float*)d_out;

    const int B = in_sizes[0] / (SEQ * DIM);

    dim3 grid(B * 8);  // 8 blocks per batch; 8 waves x 32 rows each
    attn_mfma<<<grid, BLOCK, 0, stream>>>(X, mask, Wq, bq, Wk, bk, Wv, bv, out);
}